// Round 6
// baseline (35.242 us; speedup 1.0000x reference)
//
#include <hip/hip_runtime.h>
#include <hip/hip_bf16.h>

#define H 256
#define R_N 256
#define F_N 1024

#define FMA4(A, s, W) \
    A.x = fmaf((s), (W).x, A.x); \
    A.y = fmaf((s), (W).y, A.y); \
    A.z = fmaf((s), (W).z, A.z); \
    A.w = fmaf((s), (W).w, A.w);

// ---------------------------------------------------------------------------
// embed: 8 rows per block, 256 threads (4 waves), k-split across waves.
// Blocks 0..31: robot (256 rows). Blocks 32..159: frontier (1024 rows).
// Activations kept transposed in LDS so matvec loops broadcast-read them.
// ---------------------------------------------------------------------------
__global__ __launch_bounds__(256) void embed_kernel(
    const float* __restrict__ rf, const float* __restrict__ ff,
    const float* __restrict__ r_w1, const float* __restrict__ r_b1,
    const float* __restrict__ r_w2, const float* __restrict__ r_b2,
    const float* __restrict__ f_w1, const float* __restrict__ f_b1,
    const float* __restrict__ f_w2, const float* __restrict__ f_b2,
    const float* __restrict__ a_w1, const float* __restrict__ a_b1,
    float* __restrict__ u, float* __restrict__ v)
{
    const int t  = threadIdx.x;
    const int wp = t >> 6;          // k-part (== wave id) 0..3
    const int c  = (t & 63) * 4;    // column base (float4)

    __shared__ float aT[H][8];      // transposed activations / embeddings
    __shared__ float red[4][8][H];  // cross-wave reduction buffer

    const bool robot = blockIdx.x < 32;
    const int  g0    = robot ? blockIdx.x * 8 : (blockIdx.x - 32) * 8;

    const float* __restrict__ x   = robot ? (rf + g0 * 4) : (ff + g0 * 3);
    const int                 ind = robot ? 4 : 3;
    const float* __restrict__ w1  = robot ? r_w1 : f_w1;
    const float* __restrict__ b1  = robot ? r_b1 : f_b1;
    const float* __restrict__ W2  = robot ? r_w2 : f_w2;
    const float* __restrict__ b2  = robot ? r_b2 : f_b2;
    const int                 k3  = robot ? 0 : H;   // row offset into a_w1
    float* __restrict__       dst = robot ? u : v;

    // ---- layer 1: col t for all 8 rows, relu, store transposed ----
    {
        float l1[8];
        const float bb = b1[t];
        #pragma unroll
        for (int g = 0; g < 8; ++g) {
            float acc = bb;
            for (int j = 0; j < ind; ++j)
                acc = fmaf(x[g * ind + j], w1[j * H + t], acc);
            l1[g] = fmaxf(acc, 0.0f);
        }
        *(float4*)&aT[t][0] = make_float4(l1[0], l1[1], l1[2], l1[3]);
        *(float4*)&aT[t][4] = make_float4(l1[4], l1[5], l1[6], l1[7]);
    }
    __syncthreads();

    // ---- layer 2: e = a @ W2 + b2 (no relu) ----
    {
        float4 acc[8];
        #pragma unroll
        for (int g = 0; g < 8; ++g) acc[g] = make_float4(0.f, 0.f, 0.f, 0.f);

        const int kbase = wp * 64;
        #pragma unroll 8
        for (int kk = 0; kk < 64; ++kk) {
            const int k = kbase + kk;
            const float4 w4  = *(const float4*)&W2[k * H + c];
            const float4 alo = *(const float4*)&aT[k][0];
            const float4 ahi = *(const float4*)&aT[k][4];
            FMA4(acc[0], alo.x, w4); FMA4(acc[1], alo.y, w4);
            FMA4(acc[2], alo.z, w4); FMA4(acc[3], alo.w, w4);
            FMA4(acc[4], ahi.x, w4); FMA4(acc[5], ahi.y, w4);
            FMA4(acc[6], ahi.z, w4); FMA4(acc[7], ahi.w, w4);
        }
        #pragma unroll
        for (int g = 0; g < 8; ++g) *(float4*)&red[wp][g][c] = acc[g];
    }
    __syncthreads();

    // ---- reduce parts, add b2, store transposed back into aT ----
    {
        float e[8];
        const float bb = b2[t];
        #pragma unroll
        for (int g = 0; g < 8; ++g)
            e[g] = red[0][g][t] + red[1][g][t] + red[2][g][t] + red[3][g][t] + bb;
        *(float4*)&aT[t][0] = make_float4(e[0], e[1], e[2], e[3]);
        *(float4*)&aT[t][4] = make_float4(e[4], e[5], e[6], e[7]);
    }
    __syncthreads();

    // ---- layer 3: u/v = e @ w1_{r|f} ----
    {
        float4 acc[8];
        #pragma unroll
        for (int g = 0; g < 8; ++g) acc[g] = make_float4(0.f, 0.f, 0.f, 0.f);

        const int kbase = wp * 64;
        #pragma unroll 8
        for (int kk = 0; kk < 64; ++kk) {
            const int k = kbase + kk;
            const float4 w4  = *(const float4*)&a_w1[(k3 + k) * H + c];
            const float4 alo = *(const float4*)&aT[k][0];
            const float4 ahi = *(const float4*)&aT[k][4];
            FMA4(acc[0], alo.x, w4); FMA4(acc[1], alo.y, w4);
            FMA4(acc[2], alo.z, w4); FMA4(acc[3], alo.w, w4);
            FMA4(acc[4], ahi.x, w4); FMA4(acc[5], ahi.y, w4);
            FMA4(acc[6], ahi.z, w4); FMA4(acc[7], ahi.w, w4);
        }
        #pragma unroll
        for (int g = 0; g < 8; ++g) *(float4*)&red[wp][g][c] = acc[g];
    }
    __syncthreads();

    // ---- final reduce + (frontier: +a_b1) + global store ----
    {
        const float ab = robot ? 0.0f : a_b1[t];
        #pragma unroll
        for (int g = 0; g < 8; ++g) {
            const float s = red[0][g][t] + red[1][g][t] + red[2][g][t] + red[3][g][t] + ab;
            dst[(g0 + g) * H + t] = s;
        }
    }
}

// ---------------------------------------------------------------------------
// affinity: out[r,f] = sum_k relu(u[r,k]+v[f,k])*w2[k] + b2
// 256 blocks (8 r-tiles x 32 f-tiles of 32x32), 512 threads (8 waves).
// k-split-4 ACROSS wave-pairs within the block; LDS reduce of the 4 partials.
// Per 128-thread group: 4x2 micro-tile per thread over its 64-k range.
// LDS stride 260 -> worst 2-way bank alias (free). No global partials:
// ws usage stays at u+v = 1.31 MB (proven safe in round 1).
// ---------------------------------------------------------------------------
#define LDP 260

__global__ __launch_bounds__(512) void affinity_kernel(
    const float* __restrict__ u, const float* __restrict__ v,
    const float* __restrict__ a_w2, const float* __restrict__ a_b2,
    float* __restrict__ out)
{
    __shared__ float u_s[32][LDP];
    __shared__ float v_s[32][LDP];
    __shared__ float w_s[H];
    __shared__ float red[4][32][33];

    const int t  = threadIdx.x;
    const int r0 = (blockIdx.x >> 5) * 32;        // 8 r-tiles
    const int f0 = (blockIdx.x & 31) * 32;        // 32 f-tiles

    // stage u/v tiles (32 rows x 256 cols each) + w
    #pragma unroll
    for (int i = 0; i < 4; ++i) {
        const int slot = t + i * 512;         // 0..2047
        const int row  = slot >> 6;           // 0..31
        const int cc   = (slot & 63) * 4;     // 0..252
        *(float4*)&u_s[row][cc] = *(const float4*)&u[(r0 + row) * H + cc];
        *(float4*)&v_s[row][cc] = *(const float4*)&v[(f0 + row) * H + cc];
    }
    if (t < 64) *(float4*)&w_s[t * 4] = *(const float4*)&a_w2[t * 4];
    __syncthreads();

    const int kp = t >> 7;       // k-part 0..3 (wave pair)
    const int t7 = t & 127;
    const int ri = t7 >> 4;      // 0..7  -> rows ri, ri+8, ri+16, ri+24
    const int fi = t7 & 15;      // 0..15 -> cols fi, fi+16
    const int k0 = kp * 64;

    float4 accA = make_float4(0.f, 0.f, 0.f, 0.f);  // rows x col fi
    float4 accB = make_float4(0.f, 0.f, 0.f, 0.f);  // rows x col fi+16

    #pragma unroll 4
    for (int kk = 0; kk < 64; kk += 4) {
        const int k = k0 + kk;
        const float4 w4 = *(const float4*)&w_s[k];
        const float4 u0 = *(const float4*)&u_s[ri][k];
        const float4 u1 = *(const float4*)&u_s[ri +  8][k];
        const float4 u2 = *(const float4*)&u_s[ri + 16][k];
        const float4 u3 = *(const float4*)&u_s[ri + 24][k];
        const float4 va = *(const float4*)&v_s[fi][k];
        const float4 vb = *(const float4*)&v_s[fi + 16][k];

        accA.x = fmaf(fmaxf(u0.x + va.x, 0.f), w4.x, accA.x);
        accA.x = fmaf(fmaxf(u0.y + va.y, 0.f), w4.y, accA.x);
        accA.x = fmaf(fmaxf(u0.z + va.z, 0.f), w4.z, accA.x);
        accA.x = fmaf(fmaxf(u0.w + va.w, 0.f), w4.w, accA.x);
        accA.y = fmaf(fmaxf(u1.x + va.x, 0.f), w4.x, accA.y);
        accA.y = fmaf(fmaxf(u1.y + va.y, 0.f), w4.y, accA.y);
        accA.y = fmaf(fmaxf(u1.z + va.z, 0.f), w4.z, accA.y);
        accA.y = fmaf(fmaxf(u1.w + va.w, 0.f), w4.w, accA.y);
        accA.z = fmaf(fmaxf(u2.x + va.x, 0.f), w4.x, accA.z);
        accA.z = fmaf(fmaxf(u2.y + va.y, 0.f), w4.y, accA.z);
        accA.z = fmaf(fmaxf(u2.z + va.z, 0.f), w4.z, accA.z);
        accA.z = fmaf(fmaxf(u2.w + va.w, 0.f), w4.w, accA.z);
        accA.w = fmaf(fmaxf(u3.x + va.x, 0.f), w4.x, accA.w);
        accA.w = fmaf(fmaxf(u3.y + va.y, 0.f), w4.y, accA.w);
        accA.w = fmaf(fmaxf(u3.z + va.z, 0.f), w4.z, accA.w);
        accA.w = fmaf(fmaxf(u3.w + va.w, 0.f), w4.w, accA.w);

        accB.x = fmaf(fmaxf(u0.x + vb.x, 0.f), w4.x, accB.x);
        accB.x = fmaf(fmaxf(u0.y + vb.y, 0.f), w4.y, accB.x);
        accB.x = fmaf(fmaxf(u0.z + vb.z, 0.f), w4.z, accB.x);
        accB.x = fmaf(fmaxf(u0.w + vb.w, 0.f), w4.w, accB.x);
        accB.y = fmaf(fmaxf(u1.x + vb.x, 0.f), w4.x, accB.y);
        accB.y = fmaf(fmaxf(u1.y + vb.y, 0.f), w4.y, accB.y);
        accB.y = fmaf(fmaxf(u1.z + vb.z, 0.f), w4.z, accB.y);
        accB.y = fmaf(fmaxf(u1.w + vb.w, 0.f), w4.w, accB.y);
        accB.z = fmaf(fmaxf(u2.x + vb.x, 0.f), w4.x, accB.z);
        accB.z = fmaf(fmaxf(u2.y + vb.y, 0.f), w4.y, accB.z);
        accB.z = fmaf(fmaxf(u2.z + vb.z, 0.f), w4.z, accB.z);
        accB.z = fmaf(fmaxf(u2.w + vb.w, 0.f), w4.w, accB.z);
        accB.w = fmaf(fmaxf(u3.x + vb.x, 0.f), w4.x, accB.w);
        accB.w = fmaf(fmaxf(u3.y + vb.y, 0.f), w4.y, accB.w);
        accB.w = fmaf(fmaxf(u3.z + vb.z, 0.f), w4.z, accB.w);
        accB.w = fmaf(fmaxf(u3.w + vb.w, 0.f), w4.w, accB.w);
    }

    // write partials to LDS
    red[kp][ri]     [fi]      = accA.x;
    red[kp][ri +  8][fi]      = accA.y;
    red[kp][ri + 16][fi]      = accA.z;
    red[kp][ri + 24][fi]      = accA.w;
    red[kp][ri]     [fi + 16] = accB.x;
    red[kp][ri +  8][fi + 16] = accB.y;
    red[kp][ri + 16][fi + 16] = accB.z;
    red[kp][ri + 24][fi + 16] = accB.w;
    __syncthreads();

    // reduce 4 k-partials + bias, write out (2 outputs per thread)
    const float b = a_b2[0];
    #pragma unroll
    for (int j = 0; j < 2; ++j) {
        const int o = t + j * 512;        // 0..1023
        const int r = o >> 5;
        const int f = o & 31;
        const float s = red[0][r][f] + red[1][r][f] + red[2][r][f] + red[3][r][f] + b;
        out[(r0 + r) * F_N + f0 + f] = s;
    }
}

extern "C" void kernel_launch(void* const* d_in, const int* in_sizes, int n_in,
                              void* d_out, int out_size, void* d_ws, size_t ws_size,
                              hipStream_t stream) {
    const float* rf   = (const float*)d_in[0];
    const float* ff   = (const float*)d_in[1];
    const float* r_w1 = (const float*)d_in[2];
    const float* r_b1 = (const float*)d_in[3];
    const float* r_w2 = (const float*)d_in[4];
    const float* r_b2 = (const float*)d_in[5];
    const float* f_w1 = (const float*)d_in[6];
    const float* f_b1 = (const float*)d_in[7];
    const float* f_w2 = (const float*)d_in[8];
    const float* f_b2 = (const float*)d_in[9];
    const float* a_w1 = (const float*)d_in[10];
    const float* a_b1 = (const float*)d_in[11];
    const float* a_w2 = (const float*)d_in[12];
    const float* a_b2 = (const float*)d_in[13];

    float* u = (float*)d_ws;                 // 256*256 f32  (256 KB)
    float* v = u + R_N * H;                  // 1024*256 f32 (1 MB)
    // total ws usage: 1.31 MB (same as the round-1 kernel that passed)

    embed_kernel<<<160, 256, 0, stream>>>(rf, ff, r_w1, r_b1, r_w2, r_b2,
                                          f_w1, f_b1, f_w2, f_b2,
                                          a_w1, a_b1, u, v);
    affinity_kernel<<<256, 512, 0, stream>>>(u, v, a_w2, a_b2, (float*)d_out);
}

// Round 7
// 33.204 us; speedup vs baseline: 1.0614x; 1.0614x over previous
//
#include <hip/hip_runtime.h>
#include <hip/hip_bf16.h>

#define H 256
#define R_N 256
#define F_N 1024
#define WC_ROWS 257   // 256 weight rows + 1 bias row

// ===========================================================================
// NEW PATH (needs ws >= u + v + Wc = 1.75 MB)
//   u = relu(rf@r_w1+r_b1) @ Wc_r          where Wc_r = r_w2 @ w1_r, bias row
//   v = relu(ff@f_w1+f_b1) @ Wc_f (+bias)  where Wc_f = f_w2 @ w1_f, bias row
//                                                 = f_b2@w1_f + a_b1
// ===========================================================================

// ---------------------------------------------------------------------------
// combine: Wc[p][i][j] = sum_k W2_p[i][k] * w1_p[k][j]   (i<256)
//          Wc[p][256][j] = b2_p @ w1_p (+ a_b1 if p==1)
// Grid: 2 paths x 33 row-tiles(8) x 8 col-tiles(32) = 528 blocks, 256 thr.
// In-block k-split-4 (wave = one k-quarter), LDS reduce.
// ---------------------------------------------------------------------------
__global__ __launch_bounds__(256) void combine_kernel(
    const float* __restrict__ r_w2, const float* __restrict__ r_b2,
    const float* __restrict__ f_w2, const float* __restrict__ f_b2,
    const float* __restrict__ a_w1, const float* __restrict__ a_b1,
    float* __restrict__ Wc)
{
    __shared__ float aT[H][12];      // A rows transposed (pad 12 -> 8-way max)
    __shared__ float red[4][8][40];  // k-part partials

    const int t    = threadIdx.x;
    const int b    = blockIdx.x;
    const int p    = b / 264;
    const int rem  = b % 264;
    const int rt   = rem >> 3;
    const int ct   = rem & 7;
    const int i0   = rt * 8;
    const int col0 = ct * 32;

    const float* __restrict__ W2  = p ? f_w2 : r_w2;
    const float* __restrict__ b2  = p ? f_b2 : r_b2;
    const float* __restrict__ w1  = a_w1 + p * H * H;
    float* __restrict__       out = Wc + p * WC_ROWS * H;

    // stage A rows i0..i0+7 transposed: A[i][k] = W2[i][k] | b2[k] | 0
    {
        float vb[8];
        #pragma unroll
        for (int g = 0; g < 8; ++g) {
            const int i = i0 + g;
            vb[g] = (i < H) ? W2[i * H + t] : ((i == H) ? b2[t] : 0.0f);
        }
        *(float4*)&aT[t][0] = make_float4(vb[0], vb[1], vb[2], vb[3]);
        *(float4*)&aT[t][4] = make_float4(vb[4], vb[5], vb[6], vb[7]);
    }
    __syncthreads();

    const int kp  = t >> 6;          // wave id = k-quarter
    const int idx = t & 63;
    const int r   = idx >> 3;        // 0..7 (A row)
    const int cl  = (idx & 7) * 4;   // 0..28 (local col, float4)

    float4 acc = make_float4(0.f, 0.f, 0.f, 0.f);
    const int kb = kp * 64;
    #pragma unroll 8
    for (int kk = 0; kk < 64; ++kk) {
        const int k = kb + kk;
        const float4 w4 = *(const float4*)&w1[k * H + col0 + cl];
        const float  a  = aT[k][r];
        acc.x = fmaf(a, w4.x, acc.x);
        acc.y = fmaf(a, w4.y, acc.y);
        acc.z = fmaf(a, w4.z, acc.z);
        acc.w = fmaf(a, w4.w, acc.w);
    }
    *(float4*)&red[kp][r][cl] = acc;
    __syncthreads();

    const int rr = t >> 5;           // 0..7
    const int cc = t & 31;           // 0..31
    const int i  = i0 + rr;
    if (i < WC_ROWS) {
        float s = red[0][rr][cc] + red[1][rr][cc] + red[2][rr][cc] + red[3][rr][cc];
        if (i == H && p == 1) s += a_b1[col0 + cc];
        out[i * H + col0 + cc] = s;
    }
}

// ---------------------------------------------------------------------------
// fused_uv: layer1 inline (cheap) + single GEMM vs combined weights.
// Grid: 160 row-tiles(8 rows: 32 robot + 128 frontier) x 8 col-tiles(32)
//     = 1280 blocks, 256 thr -> ~5 waves/SIMD (latency hidden).
// ---------------------------------------------------------------------------
__global__ __launch_bounds__(256) void fused_uv_kernel(
    const float* __restrict__ rf, const float* __restrict__ ff,
    const float* __restrict__ r_w1, const float* __restrict__ r_b1,
    const float* __restrict__ f_w1, const float* __restrict__ f_b1,
    const float* __restrict__ Wc,
    float* __restrict__ u, float* __restrict__ v)
{
    __shared__ float aT[H][12];
    __shared__ float red[4][8][40];

    const int t    = threadIdx.x;
    const int rt   = blockIdx.x >> 3;
    const int ct   = blockIdx.x & 7;
    const bool robot = rt < 32;
    const int g0   = robot ? rt * 8 : (rt - 32) * 8;
    const int col0 = ct * 32;
    const float* __restrict__ Wcb = Wc + (robot ? 0 : WC_ROWS * H);

    // ---- layer 1 for the 8 rows, relu, store transposed ----
    {
        const float* __restrict__ x  = robot ? rf : ff;
        const float* __restrict__ w1 = robot ? r_w1 : f_w1;
        const float bb = (robot ? r_b1 : f_b1)[t];
        const int   nd = robot ? 4 : 3;
        float l[8];
        #pragma unroll
        for (int g = 0; g < 8; ++g) {
            float acc = bb;
            for (int j = 0; j < nd; ++j)
                acc = fmaf(x[(g0 + g) * nd + j], w1[j * H + t], acc);
            l[g] = fmaxf(acc, 0.0f);
        }
        *(float4*)&aT[t][0] = make_float4(l[0], l[1], l[2], l[3]);
        *(float4*)&aT[t][4] = make_float4(l[4], l[5], l[6], l[7]);
    }
    __syncthreads();

    const int kp  = t >> 6;
    const int idx = t & 63;
    const int r   = idx >> 3;
    const int cl  = (idx & 7) * 4;

    float4 acc = make_float4(0.f, 0.f, 0.f, 0.f);
    const int kb = kp * 64;
    #pragma unroll 8
    for (int kk = 0; kk < 64; ++kk) {
        const int k = kb + kk;
        const float4 w4 = *(const float4*)&Wcb[k * H + col0 + cl];
        const float  a  = aT[k][r];
        acc.x = fmaf(a, w4.x, acc.x);
        acc.y = fmaf(a, w4.y, acc.y);
        acc.z = fmaf(a, w4.z, acc.z);
        acc.w = fmaf(a, w4.w, acc.w);
    }
    *(float4*)&red[kp][r][cl] = acc;
    __syncthreads();

    const int rr  = t >> 5;
    const int cc  = t & 31;
    const int col = col0 + cc;
    float s = red[0][rr][cc] + red[1][rr][cc] + red[2][rr][cc] + red[3][rr][cc]
            + Wcb[H * H + col];                   // bias row (index 256)
    if (robot) u[(g0 + rr) * H + col] = s;
    else       v[(g0 + rr) * H + col] = s;
}

// ===========================================================================
// FALLBACK PATH (proven round-6 embed, used only if ws too small)
// ===========================================================================
#define FMA4(A, s, W) \
    A.x = fmaf((s), (W).x, A.x); \
    A.y = fmaf((s), (W).y, A.y); \
    A.z = fmaf((s), (W).z, A.z); \
    A.w = fmaf((s), (W).w, A.w);

__global__ __launch_bounds__(256) void embed_kernel(
    const float* __restrict__ rf, const float* __restrict__ ff,
    const float* __restrict__ r_w1, const float* __restrict__ r_b1,
    const float* __restrict__ r_w2, const float* __restrict__ r_b2,
    const float* __restrict__ f_w1, const float* __restrict__ f_b1,
    const float* __restrict__ f_w2, const float* __restrict__ f_b2,
    const float* __restrict__ a_w1, const float* __restrict__ a_b1,
    float* __restrict__ u, float* __restrict__ v)
{
    const int t  = threadIdx.x;
    const int wp = t >> 6;
    const int c  = (t & 63) * 4;

    __shared__ float aT[H][8];
    __shared__ float red[4][8][H];

    const bool robot = blockIdx.x < 32;
    const int  g0    = robot ? blockIdx.x * 8 : (blockIdx.x - 32) * 8;

    const float* __restrict__ x   = robot ? (rf + g0 * 4) : (ff + g0 * 3);
    const int                 ind = robot ? 4 : 3;
    const float* __restrict__ w1  = robot ? r_w1 : f_w1;
    const float* __restrict__ b1  = robot ? r_b1 : f_b1;
    const float* __restrict__ W2  = robot ? r_w2 : f_w2;
    const float* __restrict__ b2  = robot ? r_b2 : f_b2;
    const int                 k3  = robot ? 0 : H;
    float* __restrict__       dst = robot ? u : v;

    {
        float l1[8];
        const float bb = b1[t];
        #pragma unroll
        for (int g = 0; g < 8; ++g) {
            float acc = bb;
            for (int j = 0; j < ind; ++j)
                acc = fmaf(x[g * ind + j], w1[j * H + t], acc);
            l1[g] = fmaxf(acc, 0.0f);
        }
        *(float4*)&aT[t][0] = make_float4(l1[0], l1[1], l1[2], l1[3]);
        *(float4*)&aT[t][4] = make_float4(l1[4], l1[5], l1[6], l1[7]);
    }
    __syncthreads();

    {
        float4 acc[8];
        #pragma unroll
        for (int g = 0; g < 8; ++g) acc[g] = make_float4(0.f, 0.f, 0.f, 0.f);
        const int kbase = wp * 64;
        #pragma unroll 8
        for (int kk = 0; kk < 64; ++kk) {
            const int k = kbase + kk;
            const float4 w4  = *(const float4*)&W2[k * H + c];
            const float4 alo = *(const float4*)&aT[k][0];
            const float4 ahi = *(const float4*)&aT[k][4];
            FMA4(acc[0], alo.x, w4); FMA4(acc[1], alo.y, w4);
            FMA4(acc[2], alo.z, w4); FMA4(acc[3], alo.w, w4);
            FMA4(acc[4], ahi.x, w4); FMA4(acc[5], ahi.y, w4);
            FMA4(acc[6], ahi.z, w4); FMA4(acc[7], ahi.w, w4);
        }
        #pragma unroll
        for (int g = 0; g < 8; ++g) *(float4*)&red[wp][g][c] = acc[g];
    }
    __syncthreads();

    {
        float e[8];
        const float bb = b2[t];
        #pragma unroll
        for (int g = 0; g < 8; ++g)
            e[g] = red[0][g][t] + red[1][g][t] + red[2][g][t] + red[3][g][t] + bb;
        *(float4*)&aT[t][0] = make_float4(e[0], e[1], e[2], e[3]);
        *(float4*)&aT[t][4] = make_float4(e[4], e[5], e[6], e[7]);
    }
    __syncthreads();

    {
        float4 acc[8];
        #pragma unroll
        for (int g = 0; g < 8; ++g) acc[g] = make_float4(0.f, 0.f, 0.f, 0.f);
        const int kbase = wp * 64;
        #pragma unroll 8
        for (int kk = 0; kk < 64; ++kk) {
            const int k = kbase + kk;
            const float4 w4  = *(const float4*)&a_w1[(k3 + k) * H + c];
            const float4 alo = *(const float4*)&aT[k][0];
            const float4 ahi = *(const float4*)&aT[k][4];
            FMA4(acc[0], alo.x, w4); FMA4(acc[1], alo.y, w4);
            FMA4(acc[2], alo.z, w4); FMA4(acc[3], alo.w, w4);
            FMA4(acc[4], ahi.x, w4); FMA4(acc[5], ahi.y, w4);
            FMA4(acc[6], ahi.z, w4); FMA4(acc[7], ahi.w, w4);
        }
        #pragma unroll
        for (int g = 0; g < 8; ++g) *(float4*)&red[wp][g][c] = acc[g];
    }
    __syncthreads();

    {
        const float ab = robot ? 0.0f : a_b1[t];
        #pragma unroll
        for (int g = 0; g < 8; ++g) {
            const float s = red[0][g][t] + red[1][g][t] + red[2][g][t] + red[3][g][t] + ab;
            dst[(g0 + g) * H + t] = s;
        }
    }
}

// ---------------------------------------------------------------------------
// affinity (unchanged, proven): out[r,f] = sum_k relu(u[r,k]+v[f,k])*w2[k]+b2
// ---------------------------------------------------------------------------
#define LDP 260

__global__ __launch_bounds__(512) void affinity_kernel(
    const float* __restrict__ u, const float* __restrict__ v,
    const float* __restrict__ a_w2, const float* __restrict__ a_b2,
    float* __restrict__ out)
{
    __shared__ float u_s[32][LDP];
    __shared__ float v_s[32][LDP];
    __shared__ float w_s[H];
    __shared__ float red[4][32][33];

    const int t  = threadIdx.x;
    const int r0 = (blockIdx.x >> 5) * 32;
    const int f0 = (blockIdx.x & 31) * 32;

    #pragma unroll
    for (int i = 0; i < 4; ++i) {
        const int slot = t + i * 512;
        const int row  = slot >> 6;
        const int cc   = (slot & 63) * 4;
        *(float4*)&u_s[row][cc] = *(const float4*)&u[(r0 + row) * H + cc];
        *(float4*)&v_s[row][cc] = *(const float4*)&v[(f0 + row) * H + cc];
    }
    if (t < 64) *(float4*)&w_s[t * 4] = *(const float4*)&a_w2[t * 4];
    __syncthreads();

    const int kp = t >> 7;
    const int t7 = t & 127;
    const int ri = t7 >> 4;
    const int fi = t7 & 15;
    const int k0 = kp * 64;

    float4 accA = make_float4(0.f, 0.f, 0.f, 0.f);
    float4 accB = make_float4(0.f, 0.f, 0.f, 0.f);

    #pragma unroll 4
    for (int kk = 0; kk < 64; kk += 4) {
        const int k = k0 + kk;
        const float4 w4 = *(const float4*)&w_s[k];
        const float4 u0 = *(const float4*)&u_s[ri][k];
        const float4 u1 = *(const float4*)&u_s[ri +  8][k];
        const float4 u2 = *(const float4*)&u_s[ri + 16][k];
        const float4 u3 = *(const float4*)&u_s[ri + 24][k];
        const float4 va = *(const float4*)&v_s[fi][k];
        const float4 vb = *(const float4*)&v_s[fi + 16][k];

        accA.x = fmaf(fmaxf(u0.x + va.x, 0.f), w4.x, accA.x);
        accA.x = fmaf(fmaxf(u0.y + va.y, 0.f), w4.y, accA.x);
        accA.x = fmaf(fmaxf(u0.z + va.z, 0.f), w4.z, accA.x);
        accA.x = fmaf(fmaxf(u0.w + va.w, 0.f), w4.w, accA.x);
        accA.y = fmaf(fmaxf(u1.x + va.x, 0.f), w4.x, accA.y);
        accA.y = fmaf(fmaxf(u1.y + va.y, 0.f), w4.y, accA.y);
        accA.y = fmaf(fmaxf(u1.z + va.z, 0.f), w4.z, accA.y);
        accA.y = fmaf(fmaxf(u1.w + va.w, 0.f), w4.w, accA.y);
        accA.z = fmaf(fmaxf(u2.x + va.x, 0.f), w4.x, accA.z);
        accA.z = fmaf(fmaxf(u2.y + va.y, 0.f), w4.y, accA.z);
        accA.z = fmaf(fmaxf(u2.z + va.z, 0.f), w4.z, accA.z);
        accA.z = fmaf(fmaxf(u2.w + va.w, 0.f), w4.w, accA.z);
        accA.w = fmaf(fmaxf(u3.x + va.x, 0.f), w4.x, accA.w);
        accA.w = fmaf(fmaxf(u3.y + va.y, 0.f), w4.y, accA.w);
        accA.w = fmaf(fmaxf(u3.z + va.z, 0.f), w4.z, accA.w);
        accA.w = fmaf(fmaxf(u3.w + va.w, 0.f), w4.w, accA.w);

        accB.x = fmaf(fmaxf(u0.x + vb.x, 0.f), w4.x, accB.x);
        accB.x = fmaf(fmaxf(u0.y + vb.y, 0.f), w4.y, accB.x);
        accB.x = fmaf(fmaxf(u0.z + vb.z, 0.f), w4.z, accB.x);
        accB.x = fmaf(fmaxf(u0.w + vb.w, 0.f), w4.w, accB.x);
        accB.y = fmaf(fmaxf(u1.x + vb.x, 0.f), w4.x, accB.y);
        accB.y = fmaf(fmaxf(u1.y + vb.y, 0.f), w4.y, accB.y);
        accB.y = fmaf(fmaxf(u1.z + vb.z, 0.f), w4.z, accB.y);
        accB.y = fmaf(fmaxf(u1.w + vb.w, 0.f), w4.w, accB.y);
        accB.z = fmaf(fmaxf(u2.x + vb.x, 0.f), w4.x, accB.z);
        accB.z = fmaf(fmaxf(u2.y + vb.y, 0.f), w4.y, accB.z);
        accB.z = fmaf(fmaxf(u2.z + vb.z, 0.f), w4.z, accB.z);
        accB.z = fmaf(fmaxf(u2.w + vb.w, 0.f), w4.w, accB.z);
        accB.w = fmaf(fmaxf(u3.x + vb.x, 0.f), w4.x, accB.w);
        accB.w = fmaf(fmaxf(u3.y + vb.y, 0.f), w4.y, accB.w);
        accB.w = fmaf(fmaxf(u3.z + vb.z, 0.f), w4.z, accB.w);
        accB.w = fmaf(fmaxf(u3.w + vb.w, 0.f), w4.w, accB.w);
    }

    red[kp][ri]     [fi]      = accA.x;
    red[kp][ri +  8][fi]      = accA.y;
    red[kp][ri + 16][fi]      = accA.z;
    red[kp][ri + 24][fi]      = accA.w;
    red[kp][ri]     [fi + 16] = accB.x;
    red[kp][ri +  8][fi + 16] = accB.y;
    red[kp][ri + 16][fi + 16] = accB.z;
    red[kp][ri + 24][fi + 16] = accB.w;
    __syncthreads();

    const float b = a_b2[0];
    #pragma unroll
    for (int j = 0; j < 2; ++j) {
        const int o = t + j * 512;
        const int r = o >> 5;
        const int f = o & 31;
        const float s = red[0][r][f] + red[1][r][f] + red[2][r][f] + red[3][r][f] + b;
        out[(r0 + r) * F_N + f0 + f] = s;
    }
}

extern "C" void kernel_launch(void* const* d_in, const int* in_sizes, int n_in,
                              void* d_out, int out_size, void* d_ws, size_t ws_size,
                              hipStream_t stream) {
    const float* rf   = (const float*)d_in[0];
    const float* ff   = (const float*)d_in[1];
    const float* r_w1 = (const float*)d_in[2];
    const float* r_b1 = (const float*)d_in[3];
    const float* r_w2 = (const float*)d_in[4];
    const float* r_b2 = (const float*)d_in[5];
    const float* f_w1 = (const float*)d_in[6];
    const float* f_b1 = (const float*)d_in[7];
    const float* f_w2 = (const float*)d_in[8];
    const float* f_b2 = (const float*)d_in[9];
    const float* a_w1 = (const float*)d_in[10];
    const float* a_b1 = (const float*)d_in[11];
    const float* a_w2 = (const float*)d_in[12];
    const float* a_b2 = (const float*)d_in[13];

    float* u  = (float*)d_ws;                  // 256*256
    float* v  = u + R_N * H;                   // 1024*256
    float* Wc = v + F_N * H;                   // 2*257*256

    const size_t need = (size_t)(R_N * H + F_N * H + 2 * WC_ROWS * H) * 4;

    if (ws_size >= need) {
        combine_kernel<<<528, 256, 0, stream>>>(r_w2, r_b2, f_w2, f_b2,
                                                a_w1, a_b1, Wc);
        fused_uv_kernel<<<1280, 256, 0, stream>>>(rf, ff, r_w1, r_b1,
                                                  f_w1, f_b1, Wc, u, v);
    } else {
        embed_kernel<<<160, 256, 0, stream>>>(rf, ff, r_w1, r_b1, r_w2, r_b2,
                                              f_w1, f_b1, f_w2, f_b2,
                                              a_w1, a_b1, u, v);
    }
    affinity_kernel<<<256, 512, 0, stream>>>(u, v, a_w2, a_b2, (float*)d_out);
}